// Round 4
// baseline (57.755 us; speedup 1.0000x reference)
//
#include <hip/hip_runtime.h>

// entmax_bisect, alpha=1.5, rows of N=2048 fp32. One wave64 per row.
// v = 0.5*x - 0.5*max  =>  max element -> exactly 0; bracket (lo,hi)=(-1,0).
// am1=0.5 => power(d,1/am1)=d*d.
//
// Key fact: every bisection midpoint and the final tau lie in (-1, 0], so
// elements with v <= -1 contribute exactly 0 to s(mid), the aggregates, and
// the final normalizing sum. For iid N(0,1) rows only ~140/2048 elements are
// candidates (v > -1). We compact candidates (<=CAPL per lane) into LDS,
// read them back to registers, and run all tau-finding on the compacted set:
//   P1: K1=6 bisect iters (bracket 2^-6), invariant s(lo) > 1 >= s(hi).
//   P2: aggregates (n,S1,S2) over certain support {v > hi}, centered at hi;
//       boundary elements in (lo,hi] compacted (<=8).
//   P3: sort boundary desc, greedy prefix-accept (s monotone), closed-form
//       root tau = hi + (S1 - sqrt(S1^2 - n(S2-1)))/n  (== 50-iter limit).
// Fallbacks (exact): lane candidate overflow -> 50 full-pass iterations on
// v[32]; boundary overflow -> 44 more bisect iterations on candidates.
// Output uses non-temporal stores so the 128 MB input stays L3-resident
// across replays (fetch -> ~0).

typedef float f32x4 __attribute__((ext_vector_type(4)));

constexpr int N = 2048;
constexpr int PER_LANE = N / 64;      // 32
constexpr int WPB = 4;                // waves per 256-thread block
constexpr int CAPL = 12;              // candidate capacity per lane
constexpr int BMAX = 8;
constexpr int K1 = 6;
constexpr int TOTAL_ITER = 50;

__device__ __forceinline__ float wave_sum(float s) {
    #pragma unroll
    for (int off = 32; off >= 1; off >>= 1)
        s += __shfl_xor(s, off, 64);
    return s;
}
__device__ __forceinline__ float wave_max(float m) {
    #pragma unroll
    for (int off = 32; off >= 1; off >>= 1)
        m = fmaxf(m, __shfl_xor(m, off, 64));
    return m;
}

__global__ __launch_bounds__(256, 6)
void entmax15_kernel(const float* __restrict__ x,
                     float* __restrict__ out, int rows) {
    __shared__ float s_cand[WPB][CAPL][64];   // slot-major: conflict-free
    __shared__ float s_bnd[WPB][BMAX];
    __shared__ int   s_cnt[WPB];

    const int wave = threadIdx.x >> 6;
    const int lane = threadIdx.x & 63;
    const int row  = blockIdx.x * WPB + wave;
    if (row >= rows) return;          // rows % WPB == 0: never divergent

    const f32x4* xr   = reinterpret_cast<const f32x4*>(x + (size_t)row * N);
    f32x4*       outr = reinterpret_cast<f32x4*>(out + (size_t)row * N);

    float v[PER_LANE];
    #pragma unroll
    for (int c = 0; c < PER_LANE / 4; ++c) {
        f32x4 t = xr[lane + 64 * c];
        v[4*c+0] = t.x; v[4*c+1] = t.y; v[4*c+2] = t.z; v[4*c+3] = t.w;
    }

    // Row max.
    float m = v[0];
    #pragma unroll
    for (int i = 1; i < PER_LANE; ++i) m = fmaxf(m, v[i]);
    m = wave_max(m);

    // v = 0.5*x - 0.5*m  (argmax -> exactly 0)
    const float nhm = -0.5f * m;
    #pragma unroll
    for (int i = 0; i < PER_LANE; ++i) v[i] = fmaf(0.5f, v[i], nhm);

    // ---- Candidate compaction: v > -1 into per-lane LDS slots ----
    #pragma unroll
    for (int k = 0; k < CAPL; ++k) s_cand[wave][k][lane] = -1e30f;
    if (lane < BMAX) s_bnd[wave][lane] = -1e30f;
    if (lane == 0)   s_cnt[wave] = 0;
    // All LDS here is wave-private; same-wave DS ordering (lgkmcnt) suffices.

    int j = 0;
    #pragma unroll
    for (int i = 0; i < PER_LANE; ++i) {
        const bool cand = v[i] > -1.0f;
        const int  slot = (j < CAPL - 1) ? j : (CAPL - 1);  // clamp (ovf caught below)
        if (cand) s_cand[wave][slot][lane] = v[i];
        j += cand ? 1 : 0;
    }

    float tau, ssum;
    if (!__any(j > CAPL)) {
        // ---- Fast path: everything on <=12 candidates/lane ----
        float cd[CAPL];
        #pragma unroll
        for (int k = 0; k < CAPL; ++k) cd[k] = s_cand[wave][k][lane];

        float lo = -1.0f, hi = 0.0f;
        for (int it = 0; it < K1; ++it) {
            const float mid = 0.5f * (lo + hi);
            float sa = 0.f, sb = 0.f;
            #pragma unroll
            for (int k = 0; k < CAPL; k += 2) {
                float d0 = fmaxf(cd[k]   - mid, 0.f);
                float d1 = fmaxf(cd[k+1] - mid, 0.f);
                sa = fmaf(d0, d0, sa);
                sb = fmaf(d1, d1, sb);
            }
            float s = wave_sum(sa + sb);
            if (s > 1.0f) lo = mid; else hi = mid;
        }

        // Aggregates over certain support + boundary compaction.
        const float cth = hi, lof = lo;
        float nA = 0.f, S1 = 0.f, S2 = 0.f;
        #pragma unroll
        for (int k = 0; k < CAPL; ++k) {
            float u  = cd[k] - cth;
            float um = fmaxf(u, 0.f);
            nA += (u > 0.f) ? 1.0f : 0.0f;
            S1 += um;
            S2  = fmaf(um, um, S2);
            if (u <= 0.f && cd[k] > lof) {          // boundary: rare
                int t = atomicAdd(&s_cnt[wave], 1);
                if (t < BMAX) s_bnd[wave][t] = cd[k];
            }
        }
        nA = wave_sum(nA); S1 = wave_sum(S1); S2 = wave_sum(S2);

        const int cnt = s_cnt[wave];                // wave-uniform
        if (cnt <= BMAX) {
            float b0 = s_bnd[wave][0], b1 = s_bnd[wave][1];
            float b2 = s_bnd[wave][2], b3 = s_bnd[wave][3];
            float b4 = s_bnd[wave][4], b5 = s_bnd[wave][5];
            float b6 = s_bnd[wave][6], b7 = s_bnd[wave][7];
            // Sort descending (Batcher, 19 CEs); sentinels sink.
            #define CE(a, b) { float _t = fmaxf(a, b); b = fminf(a, b); a = _t; }
            CE(b0,b1) CE(b2,b3) CE(b4,b5) CE(b6,b7)
            CE(b0,b2) CE(b1,b3) CE(b4,b6) CE(b5,b7)
            CE(b1,b2) CE(b5,b6)
            CE(b0,b4) CE(b1,b5) CE(b2,b6) CE(b3,b7)
            CE(b2,b4) CE(b3,b5)
            CE(b1,b2) CE(b3,b4) CE(b5,b6)
            #undef CE
            // Greedy prefix-accept (sentinels: s=+inf => reject).
            float nk = nA, S1k = S1, S2k = S2;
            #define STEP(bk) {                                              \
                float t_  = bk - cth;                                       \
                float sc_ = fmaf(t_, fmaf(nk, t_, -2.0f * S1k), S2k);       \
                bool  ac_ = sc_ < 1.0f;                                     \
                float ta_ = ac_ ? t_ : 0.0f;                                \
                nk  += ac_ ? 1.0f : 0.0f;                                   \
                S1k += ta_;                                                 \
                S2k  = fmaf(ta_, ta_, S2k); }
            STEP(b0) STEP(b1) STEP(b2) STEP(b3)
            STEP(b4) STEP(b5) STEP(b6) STEP(b7)
            #undef STEP
            float disc = fmaxf(fmaf(S1k, S1k, -nk * (S2k - 1.0f)), 0.0f);
            tau = cth + (S1k - sqrtf(disc)) / nk;
        } else {
            // Boundary overflow: finish all remaining iterations (exact,
            // still on the compacted set — non-candidates contribute 0).
            for (int it = 0; it < TOTAL_ITER - K1; ++it) {
                const float mid = 0.5f * (lo + hi);
                float sa = 0.f, sb = 0.f;
                #pragma unroll
                for (int k = 0; k < CAPL; k += 2) {
                    float d0 = fmaxf(cd[k]   - mid, 0.f);
                    float d1 = fmaxf(cd[k+1] - mid, 0.f);
                    sa = fmaf(d0, d0, sa);
                    sb = fmaf(d1, d1, sb);
                }
                float s = wave_sum(sa + sb);
                if (s > 1.0f) lo = mid; else hi = mid;
            }
            tau = 0.5f * (lo + hi);
        }

        // Normalizing sum from candidates (non-candidates are exactly 0).
        float sa = 0.f, sb = 0.f;
        #pragma unroll
        for (int k = 0; k < CAPL; k += 2) {
            float d0 = fmaxf(cd[k]   - tau, 0.f);
            float d1 = fmaxf(cd[k+1] - tau, 0.f);
            sa = fmaf(d0, d0, sa);
            sb = fmaf(d1, d1, sb);
        }
        ssum = wave_sum(sa + sb);
    } else {
        // ---- Lane-overflow fallback: full 50-iteration bisection on v ----
        float lo = -1.0f, hi = 0.0f;
        for (int it = 0; it < TOTAL_ITER; ++it) {
            const float mid = 0.5f * (lo + hi);
            float s0 = 0.f, s1_ = 0.f, s2_ = 0.f, s3_ = 0.f;
            #pragma unroll
            for (int i = 0; i < PER_LANE; i += 4) {
                float d0 = fmaxf(v[i+0] - mid, 0.f);
                float d1 = fmaxf(v[i+1] - mid, 0.f);
                float d2 = fmaxf(v[i+2] - mid, 0.f);
                float d3 = fmaxf(v[i+3] - mid, 0.f);
                s0 = fmaf(d0, d0, s0); s1_ = fmaf(d1, d1, s1_);
                s2_ = fmaf(d2, d2, s2_); s3_ = fmaf(d3, d3, s3_);
            }
            float s = wave_sum((s0 + s1_) + (s2_ + s3_));
            if (s > 1.0f) lo = mid; else hi = mid;
        }
        tau = 0.5f * (lo + hi);
        float s0 = 0.f;
        #pragma unroll
        for (int i = 0; i < PER_LANE; ++i) {
            float d = fmaxf(v[i] - tau, 0.f);
            s0 = fmaf(d, d, s0);
        }
        ssum = wave_sum(s0);
    }

    // ---- Epilogue: p = max(v - tau, 0)^2 * inv, non-temporal stores ----
    const float inv = 1.0f / fmaxf(ssum, 1e-12f);
    #pragma unroll
    for (int c = 0; c < PER_LANE / 4; ++c) {
        float d0 = fmaxf(v[4*c+0] - tau, 0.f);
        float d1 = fmaxf(v[4*c+1] - tau, 0.f);
        float d2 = fmaxf(v[4*c+2] - tau, 0.f);
        float d3 = fmaxf(v[4*c+3] - tau, 0.f);
        f32x4 t;
        t.x = (d0 * d0) * inv;
        t.y = (d1 * d1) * inv;
        t.z = (d2 * d2) * inv;
        t.w = (d3 * d3) * inv;
        __builtin_nontemporal_store(t, &outr[lane + 64 * c]);
    }
}

extern "C" void kernel_launch(void* const* d_in, const int* in_sizes, int n_in,
                              void* d_out, int out_size, void* d_ws, size_t ws_size,
                              hipStream_t stream) {
    const float* x = (const float*)d_in[0];
    float* out = (float*)d_out;
    const int rows = in_sizes[0] / N;                       // 16384
    const int blocks = (rows + WPB - 1) / WPB;
    entmax15_kernel<<<blocks, 64 * WPB, 0, stream>>>(x, out, rows);
}